// Round 7
// baseline (542.367 us; speedup 1.0000x reference)
//
#include <hip/hip_runtime.h>
#include <hip/hip_bf16.h>
#include <cstdint>

#define N_NODES 50000
#define N_EDGES 800000
#define EPS_BN 1e-5f

typedef short s16x8 __attribute__((ext_vector_type(8)));   // 8 bf16 = 4 VGPRs
typedef float f32x4 __attribute__((ext_vector_type(4)));

__device__ __forceinline__ ushort f2b(float f) {
    uint u = __float_as_uint(f);
    u += 0x7fffu + ((u >> 16) & 1u);
    return (ushort)(u >> 16);
}
__device__ __forceinline__ float b2f(ushort b) {
    return __uint_as_float(((uint)b) << 16);
}

// ---------------- encoder: x(N,19) -> h0(N,96) bf16 = [sp(32), fe(64)] ----------------
__global__ __launch_bounds__(128) void encoder_kernel(
    const float* __restrict__ x,
    const float* __restrict__ sp_w1, const float* __restrict__ sp_b1,
    const float* __restrict__ sp_w2, const float* __restrict__ sp_b2,
    const float* __restrict__ fe_w, const float* __restrict__ fe_b,
    ushort* __restrict__ h0)
{
    __shared__ float w1[96], b1[32], w2[1024], b2[32], wf[1024], bf[64];
    __shared__ float outt[128 * 97];
    int tid = threadIdx.x;
    for (int i = tid; i < 96; i += 128) w1[i] = sp_w1[i];
    for (int i = tid; i < 32; i += 128) { b1[i] = sp_b1[i]; b2[i] = sp_b2[i]; }
    for (int i = tid; i < 1024; i += 128) { w2[i] = sp_w2[i]; wf[i] = fe_w[i]; }
    for (int i = tid; i < 64; i += 128) bf[i] = fe_b[i];
    __syncthreads();
    int n = blockIdx.x * 128 + tid;
    if (n < N_NODES) {
        float c0 = x[n*19+0], c1 = x[n*19+1], c2 = x[n*19+2];
        float ft[16];
        #pragma unroll
        for (int i = 0; i < 16; i++) ft[i] = x[n*19+3+i];
        float t1[32];
        #pragma unroll
        for (int j = 0; j < 32; j++)
            t1[j] = fmaxf(c0*w1[j] + c1*w1[32+j] + c2*w1[64+j] + b1[j], 0.f);
        #pragma unroll 4
        for (int j = 0; j < 32; j++) {
            float a = b2[j];
            #pragma unroll
            for (int k = 0; k < 32; k++) a += t1[k]*w2[k*32+j];
            outt[tid*97+j] = fmaxf(a, 0.f);
        }
        #pragma unroll 4
        for (int j = 0; j < 64; j++) {
            float a = bf[j];
            #pragma unroll
            for (int k = 0; k < 16; k++) a += ft[k]*wf[k*64+j];
            outt[tid*97+32+j] = fmaxf(a, 0.f);
        }
    }
    __syncthreads();
    int base = blockIdx.x * 128;
    int nv = min(128, N_NODES - base);
    for (int i = tid; i < nv*96; i += 128) {
        int r = i / 96, c = i - r*96;
        h0[(size_t)base*96 + i] = f2b(outt[r*97 + c]);
    }
}

// ---------------- CSR build ----------------
// One packed 64-bit atomic per edge: count in bits [40,64), degw in 23.0 fixed point
// below (max sum ~2^30 << 2^40, no carry into count). Returned old>>40 = edge rank.
__global__ void deg_kernel(const int* __restrict__ dst, const float* __restrict__ ew,
                           unsigned long long* __restrict__ pk, int* __restrict__ rank)
{
    int e = blockIdx.x*256 + threadIdx.x;
    if (e < N_EDGES) {
        int d = dst[e];
        unsigned long long inc = (1ull << 40)
            + (unsigned long long)(uint)(ew[e]*8388608.f + 0.5f);
        unsigned long long old = atomicAdd(&pk[d], inc);
        rank[e] = (int)(old >> 40);
    }
}

// scan phase A (+ fused prep): per-1024 chunk exclusive scan + chunk totals
__global__ __launch_bounds__(1024) void scan_a(const unsigned long long* __restrict__ pk,
                                               int* __restrict__ rowptr,
                                               int* __restrict__ bsum,
                                               float* __restrict__ inv_cnt,
                                               float* __restrict__ dis)
{
    __shared__ int wsum[16];
    int tid = threadIdx.x;
    int i = blockIdx.x*1024 + tid;
    int v = 0;
    if (i < N_NODES) {
        unsigned long long u = pk[i];
        v = (int)(u >> 40);
        float dw = (float)(u & ((1ull<<40)-1)) * (1.f/8388608.f);
        inv_cnt[i] = 1.f / (float)max(v, 1);
        dis[i] = rsqrtf(dw + 1.f);   // +1 self-loop weight; always > 0
    }
    int lane = tid & 63, wid = tid >> 6;
    int incl = v;
    #pragma unroll
    for (int off = 1; off < 64; off <<= 1) {
        int t = __shfl_up(incl, off);
        if (lane >= off) incl += t;
    }
    if (lane == 63) wsum[wid] = incl;
    __syncthreads();
    if (wid == 0 && lane < 16) {
        int s = wsum[lane];
        #pragma unroll
        for (int off = 1; off < 16; off <<= 1) {
            int t = __shfl_up(s, off);
            if (lane >= off) s += t;
        }
        wsum[lane] = s;
    }
    __syncthreads();
    int base = (wid > 0) ? wsum[wid-1] : 0;
    if (i < N_NODES) rowptr[i] = base + incl - v;
    if (tid == 1023) bsum[blockIdx.x] = base + incl;
}

// scan phase C (fused B): every block re-scans the 49 chunk totals in wave 0
__global__ __launch_bounds__(256) void scan_c(int* __restrict__ rowptr,
                                              const int* __restrict__ bsum)
{
    __shared__ int boff[64];
    int tid = threadIdx.x;
    if (tid < 64) {
        const int NC = (N_NODES + 1023) >> 10;   // 49
        int v = (tid < NC) ? bsum[tid] : 0;
        int incl = v;
        #pragma unroll
        for (int off = 1; off < 64; off <<= 1) {
            int t = __shfl_up(incl, off);
            if (tid >= off) incl += t;
        }
        boff[tid] = incl - v;   // exclusive; boff[NC] = grand total
    }
    __syncthreads();
    int i = blockIdx.x*256 + tid;
    if (i < N_NODES) rowptr[i] += boff[i >> 10];
    else if (i == N_NODES) rowptr[i] = boff[(N_NODES + 1023) >> 10];
}

// scatter (no atomics): pos = rowptr[dst] + rank; edge = {src, ew*dis[src]}
__global__ void scatter_kernel(const int* __restrict__ src, const int* __restrict__ dst,
                               const float* __restrict__ ew, const float* __restrict__ dis,
                               const int* __restrict__ rowptr, const int* __restrict__ rank,
                               int2* __restrict__ edge)
{
    int e = blockIdx.x*256 + threadIdx.x;
    if (e < N_EDGES) {
        int d = dst[e];
        int s = src[e];
        int pos = rowptr[d] + rank[e];
        edge[pos] = make_int2(s, __float_as_int(ew[e] * dis[s]));
    }
}

// ---------------- aggregation: 4 nodes per wave, 64 gathers in flight ----------------
// Each wave owns 4 consecutive nodes. Batch-0 issues the first <=16 edges of ALL 4
// nodes as one flat block of 64 independent gathers (90% of edges); per-node masked
// 16-wide loops mop up the Poisson tail. Edge data is wave-uniform -> scalar regs
// (s_load + SGPR-base gather addressing); masked slots use edge[0] with weight 0.
template<int LDH, int LDO, int D2, bool GCN>
__global__ __launch_bounds__(256) void agg_batch(
    const ushort* __restrict__ h,
    const int* __restrict__ rowptr, const int2* __restrict__ edge,
    const float* __restrict__ scale,   // inv_cnt (SAGE) or dis (GCN)
    ushort* __restrict__ outp)
{
    int w = threadIdx.x >> 6, l = threadIdx.x & 63;
    int n0 = (blockIdx.x*4 + w)*4;
    if (n0 >= N_NODES) return;
    bool act = l < D2;
    int off = 2*l;

    int beg[4], end[4];
    #pragma unroll
    for (int t = 0; t < 4; t++) {
        int n = min(n0 + t, N_NODES-1);
        beg[t] = __builtin_amdgcn_readfirstlane(rowptr[n]);
        end[t] = __builtin_amdgcn_readfirstlane(rowptr[n+1]);
        if (n0 + t >= N_NODES) end[t] = beg[t];
    }

    float ax[4], ay[4];
    #pragma unroll
    for (int t = 0; t < 4; t++) { ax[t] = 0.f; ay[t] = 0.f; }

    // ---- batch-0: first 16 edges of each of the 4 nodes, flat 64-deep ----
    int   ss[64];
    float sw[64];
    #pragma unroll
    for (int t = 0; t < 4; t++)
        #pragma unroll
        for (int q = 0; q < 16; q++) {
            int j = beg[t] + q;
            bool ok = j < end[t];
            int2 e = edge[ok ? j : 0];
            ss[t*16+q] = __builtin_amdgcn_readfirstlane(e.x);
            float wv = GCN ? __int_as_float(__builtin_amdgcn_readfirstlane(e.y)) : 1.f;
            sw[t*16+q] = ok ? wv : 0.f;
        }
    if (act) {
        uint u[64];
        #pragma unroll
        for (int i = 0; i < 64; i++)
            u[i] = *(const uint*)(h + (size_t)ss[i]*LDH + off);
        #pragma unroll
        for (int t = 0; t < 4; t++)
            #pragma unroll
            for (int q = 0; q < 16; q++) {
                float m = sw[t*16+q];
                uint v = u[t*16+q];
                ax[t] = fmaf(m, __uint_as_float(v<<16), ax[t]);
                ay[t] = fmaf(m, __uint_as_float(v & 0xffff0000u), ay[t]);
            }
    }

    // ---- remainder: nodes with deg > 16 (rare path, ~10% of edges) ----
    #pragma unroll
    for (int t = 0; t < 4; t++) {
        for (int j0 = beg[t] + 16; j0 < end[t]; j0 += 16) {
            int s2[16]; float w2[16];
            #pragma unroll
            for (int q = 0; q < 16; q++) {
                int j = j0 + q;
                bool ok = j < end[t];
                int2 e = edge[ok ? j : 0];
                s2[q] = __builtin_amdgcn_readfirstlane(e.x);
                float wv = GCN ? __int_as_float(__builtin_amdgcn_readfirstlane(e.y)) : 1.f;
                w2[q] = ok ? wv : 0.f;
            }
            if (act) {
                uint uu[16];
                #pragma unroll
                for (int q = 0; q < 16; q++)
                    uu[q] = *(const uint*)(h + (size_t)s2[q]*LDH + off);
                #pragma unroll
                for (int q = 0; q < 16; q++) {
                    ax[t] = fmaf(w2[q], __uint_as_float(uu[q]<<16), ax[t]);
                    ay[t] = fmaf(w2[q], __uint_as_float(uu[q] & 0xffff0000u), ay[t]);
                }
            }
        }
    }

    // ---- finalize + store ----
    #pragma unroll
    for (int t = 0; t < 4; t++) {
        int n = n0 + t;
        if (n < N_NODES && act) {
            if (GCN) {
                float dn = scale[n];
                uint us = *(const uint*)(h + (size_t)n*LDH + off);
                float rx = dn*ax[t] + dn*dn*__uint_as_float(us<<16);
                float ry = dn*ay[t] + dn*dn*__uint_as_float(us & 0xffff0000u);
                *(uint*)(outp + (size_t)n*LDO + off) = (uint)f2b(rx) | ((uint)f2b(ry) << 16);
            } else {
                float ic = scale[n];
                *(uint*)(outp + (size_t)n*LDO + off) = (uint)f2b(ax[t]*ic) | ((uint)f2b(ay[t]*ic) << 16);
            }
        }
    }
}

// ---------------- weight prep: all 6 weights in one kernel ----------------
__device__ __forceinline__ void wprep(int idx, int K1, int KT, int NOUT,
                                      const float* __restrict__ w1,
                                      const float* __restrict__ w2,
                                      ushort* __restrict__ dst)
{
    int k = idx / NOUT, c = idx - k*NOUT;
    float v = (k < K1) ? w1[idx] : w2[idx - K1*NOUT];
    dst[c*KT + k] = f2b(v);
}

__global__ void prep_w_all(
    const float* __restrict__ c1_wl, const float* __restrict__ c1_wr,
    const float* __restrict__ c2_w,  const float* __restrict__ c3_wl,
    const float* __restrict__ c3_wr, const float* __restrict__ c4_w,
    const float* __restrict__ fu_w,  const float* __restrict__ cl_w1,
    ushort* __restrict__ wt1, ushort* __restrict__ wt2, ushort* __restrict__ wt3,
    ushort* __restrict__ wt4, ushort* __restrict__ wtF, ushort* __restrict__ wtC1)
{
    int idx = blockIdx.x*256 + threadIdx.x;
    if      (idx <  24576) wprep(idx,          96, 192, 128, c1_wl, c1_wr, wt1);
    else if (idx <  40960) wprep(idx - 24576, 128, 128, 128, c2_w,  c2_w,  wt2);
    else if (idx <  73728) wprep(idx - 40960, 128, 256, 128, c3_wl, c3_wr, wt3);
    else if (idx <  90112) wprep(idx - 73728, 128, 128, 128, c4_w,  c4_w,  wt4);
    else if (idx < 122880) wprep(idx - 90112, 128, 256, 128, fu_w,  fu_w + 16384, wtF);
    else if (idx < 131072) wprep(idx - 122880,128, 128,  64, cl_w1, cl_w1, wtC1);
}

// ---------------- MFMA GEMM: C = [A1|A2] @ W + bias (bf16 in, bf16 out, fp32 acc) -----
// 64 rows/block (4 waves x 16 rows). W staged into LDS in K-chunks of 128 (padded rows,
// 2-way-free bank pattern); A fragments (the HBM stream) fully prefetched up front so
// their latency hides under W staging. Epilogue reuses the W LDS (dead) for coalesced
// store staging + BN stats reduction.
template<int KT, int K1, int NOUT, bool RELU, bool STATS>
__global__ __launch_bounds__(256, 4) void gemm_mfma(
    const ushort* __restrict__ A1, int lda1,
    const ushort* __restrict__ A2, int lda2,
    const ushort* __restrict__ Wt,
    const float* __restrict__ bias,
    ushort* __restrict__ C, int ldc,
    float* __restrict__ stats)
{
    constexpr int NCF = NOUT/16;            // 16-col fragments
    constexpr int LW  = 136;                // padded LDS W row (ushorts): 128 + 8
    constexpr int LC  = NOUT + 8;           // padded cst row
    constexpr int NPH = (KT + 127)/128;     // K chunks
    __shared__ __align__(16) char smem[NOUT*LW*2];
    ushort (*wlds)[LW] = (ushort(*)[LW])smem;                   // phase-live
    ushort (*cst)[16][LC] = (ushort(*)[16][LC])smem;            // epilogue (W dead)
    float* red = (float*)(smem + 4*16*LC*2);                    // after cst

    int tid = threadIdx.x;
    int w = tid >> 6, l = tid & 63;
    int l15 = l & 15, l4 = l >> 4;
    int rb = blockIdx.x*64 + w*16;

    int rowA = min(rb + l15, N_NODES-1);
    const ushort* pa1 = A1 + (size_t)rowA*lda1 + 8*l4;
    const ushort* pa2 = A2 + (size_t)rowA*lda2 + 8*l4;

    // prefetch ALL A fragments (independent dwordx4 HBM loads, hide under W staging)
    s16x8 a[KT/32];
    #pragma unroll
    for (int ks = 0; ks < KT/32; ks++) {
        const int k0 = ks*32;
        a[ks] = *(const s16x8*)((k0 < K1) ? (pa1 + k0) : (pa2 + (k0 - K1)));
    }

    f32x4 acc[NCF];
    #pragma unroll
    for (int cf = 0; cf < NCF; cf++) acc[cf] = (f32x4){0.f, 0.f, 0.f, 0.f};

    #pragma unroll
    for (int ph = 0; ph < NPH; ph++) {
        const int kb = ph*128;
        const int ck = (KT - kb < 128) ? (KT - kb) : 128;
        // stage W[:, kb:kb+ck] -> wlds (coalesced global read, padded LDS write)
        for (int c = tid; c < NOUT*(ck/8); c += 256) {
            int row = c / (ck/8), kc = c - row*(ck/8);
            s16x8 v = *(const s16x8*)(Wt + (size_t)row*KT + kb + kc*8);
            *(s16x8*)&wlds[row][kc*8] = v;
        }
        __syncthreads();
        #pragma unroll
        for (int kl = 0; kl < 128; kl += 32) {
            if (kl < ck) {
                s16x8 b[NCF];
                #pragma unroll
                for (int cf = 0; cf < NCF; cf++)
                    b[cf] = *(const s16x8*)&wlds[cf*16 + l15][kl + 8*l4];
                #pragma unroll
                for (int cf = 0; cf < NCF; cf++)
                    acc[cf] = __builtin_amdgcn_mfma_f32_16x16x32_bf16(a[(kb+kl)/32], b[cf], acc[cf], 0, 0, 0);
            }
        }
        __syncthreads();   // wlds dead after last phase -> safe to reuse as cst
    }

    // epilogue: bias(+relu), stats partials, stage to LDS (per-wave region, no barrier)
    float r1[NCF], r2[NCF];
    #pragma unroll
    for (int cf = 0; cf < NCF; cf++) {
        int colc = cf*16 + l15;
        float bv = bias[colc];
        float s1 = 0.f, s2 = 0.f;
        #pragma unroll
        for (int reg = 0; reg < 4; reg++) {
            int lr = l4*4 + reg;
            float v = acc[cf][reg] + bv;
            if (RELU) v = fmaxf(v, 0.f);
            if (STATS && (rb + lr < N_NODES)) { s1 += v; s2 += v*v; }
            cst[w][lr][colc] = f2b(v);
        }
        if (STATS) {
            s1 += __shfl_xor(s1, 16); s1 += __shfl_xor(s1, 32);
            s2 += __shfl_xor(s2, 16); s2 += __shfl_xor(s2, 32);
            r1[cf] = s1; r2[cf] = s2;
        }
    }

    // coalesced store-back (wave-private cst; in-wave lgkmcnt ordering only)
    constexpr int CHK = NOUT/8;              // 16B chunks per row
    constexpr int RPI = 64/CHK;              // rows per instruction
    #pragma unroll
    for (int it = 0; it < 16/RPI; it++) {
        int lr = it*RPI + l/CHK;
        int ck2 = l % CHK;
        int r = rb + lr;
        if (r < N_NODES) {
            s16x8 v = *(const s16x8*)&cst[w][lr][ck2*8];
            *(s16x8*)&C[(size_t)r*ldc + ck2*8] = v;
        }
    }

    if (STATS) {
        for (int i = tid; i < 2*NOUT; i += 256) red[i] = 0.f;
        __syncthreads();
        if (l4 == 0) {
            #pragma unroll
            for (int cf = 0; cf < NCF; cf++) {
                atomicAdd(&red[cf*16 + l15], r1[cf]);
                atomicAdd(&red[NOUT + cf*16 + l15], r2[cf]);
            }
        }
        __syncthreads();
        for (int i = tid; i < 2*NOUT; i += 256)
            atomicAdd(&stats[i], red[i]);
    }
}

// ---------------- BN + ReLU in place on bf16 (N x 128) ----------------
__global__ __launch_bounds__(256) void bnrelu_kernel(
    ushort* __restrict__ h, const float* __restrict__ stats,
    const float* __restrict__ g, const float* __restrict__ b)
{
    __shared__ float sc[128], sh[128];
    int tid = threadIdx.x;
    if (tid < 128) {
        float mu  = stats[tid] * (1.f/N_NODES);
        float var = stats[128+tid] * (1.f/N_NODES) - mu*mu;
        float s = g[tid] * rsqrtf(var + EPS_BN);
        sc[tid] = s;
        sh[tid] = b[tid] - mu*s;
    }
    __syncthreads();
    const int total = N_NODES * 16;   // uint4 chunks of 8 bf16
    for (int i = blockIdx.x*256 + tid; i < total; i += gridDim.x*256) {
        uint4 u = ((const uint4*)h)[i];
        int c = (i & 15) * 8;
        float v0 = __uint_as_float(u.x<<16),  v1 = __uint_as_float(u.x & 0xffff0000u);
        float v2 = __uint_as_float(u.y<<16),  v3 = __uint_as_float(u.y & 0xffff0000u);
        float v4 = __uint_as_float(u.z<<16),  v5 = __uint_as_float(u.z & 0xffff0000u);
        float v6 = __uint_as_float(u.w<<16),  v7 = __uint_as_float(u.w & 0xffff0000u);
        v0 = fmaxf(v0*sc[c+0] + sh[c+0], 0.f);
        v1 = fmaxf(v1*sc[c+1] + sh[c+1], 0.f);
        v2 = fmaxf(v2*sc[c+2] + sh[c+2], 0.f);
        v3 = fmaxf(v3*sc[c+3] + sh[c+3], 0.f);
        v4 = fmaxf(v4*sc[c+4] + sh[c+4], 0.f);
        v5 = fmaxf(v5*sc[c+5] + sh[c+5], 0.f);
        v6 = fmaxf(v6*sc[c+6] + sh[c+6], 0.f);
        v7 = fmaxf(v7*sc[c+7] + sh[c+7], 0.f);
        u.x = (uint)f2b(v0) | ((uint)f2b(v1)<<16);
        u.y = (uint)f2b(v2) | ((uint)f2b(v3)<<16);
        u.z = (uint)f2b(v4) | ((uint)f2b(v5)<<16);
        u.w = (uint)f2b(v6) | ((uint)f2b(v7)<<16);
        ((uint4*)h)[i] = u;
    }
}

// ---------------- classifier head 2: out = hc(N,64)bf16 @ w2(64,10) + b2 -> fp32 ----------
__global__ __launch_bounds__(128) void cl2_kernel(
    const ushort* __restrict__ hc, const float* __restrict__ w2,
    const float* __restrict__ b2, float* __restrict__ out)
{
    __shared__ float tile[128][65];
    __shared__ float wl[640];
    __shared__ float bl[16];
    __shared__ float ol[1280];
    int tid = threadIdx.x;
    int base = blockIdx.x * 128;
    int nv = min(128, N_NODES - base);
    for (int i = tid; i < 640; i += 128) wl[i] = w2[i];
    if (tid < 10) bl[tid] = b2[tid];
    for (int i = tid; i < nv*64; i += 128) {
        int r = i >> 6, c = i & 63;
        tile[r][c] = b2f(hc[(size_t)base*64 + i]);
    }
    __syncthreads();
    if (tid < nv) {
        float o[10];
        #pragma unroll
        for (int j = 0; j < 10; j++) o[j] = bl[j];
        #pragma unroll 4
        for (int k = 0; k < 64; k++) {
            float hv = tile[tid][k];
            #pragma unroll
            for (int j = 0; j < 10; j++) o[j] += hv * wl[k*10+j];
        }
        #pragma unroll
        for (int j = 0; j < 10; j++) ol[tid*10+j] = o[j];
    }
    __syncthreads();
    for (int i = tid; i < nv*10; i += 128) out[(size_t)base*10 + i] = ol[i];
}

// ---------------- launch ----------------
extern "C" void kernel_launch(void* const* d_in, const int* in_sizes, int n_in,
                              void* d_out, int out_size, void* d_ws, size_t ws_size,
                              hipStream_t stream)
{
    const float* x     = (const float*)d_in[0];
    const int*   ei    = (const int*)  d_in[1];
    const float* ew    = (const float*)d_in[2];
    const float* sp_w1 = (const float*)d_in[3];
    const float* sp_b1 = (const float*)d_in[4];
    const float* sp_w2 = (const float*)d_in[5];
    const float* sp_b2 = (const float*)d_in[6];
    const float* fe_w  = (const float*)d_in[7];
    const float* fe_b  = (const float*)d_in[8];
    const float* c1_wl = (const float*)d_in[9];
    const float* c1_wr = (const float*)d_in[10];
    const float* c1_b  = (const float*)d_in[11];
    const float* c2_w  = (const float*)d_in[12];
    const float* c2_b  = (const float*)d_in[13];
    const float* c3_wl = (const float*)d_in[14];
    const float* c3_wr = (const float*)d_in[15];
    const float* c3_b  = (const float*)d_in[16];
    const float* c4_w  = (const float*)d_in[17];
    const float* c4_b  = (const float*)d_in[18];
    const float* bn_g  = (const float*)d_in[19];
    const float* bn_b  = (const float*)d_in[20];
    const float* fu_w  = (const float*)d_in[21];
    const float* fu_b  = (const float*)d_in[22];
    const float* cl_w1 = (const float*)d_in[23];
    const float* cl_b1 = (const float*)d_in[24];
    const float* cl_w2 = (const float*)d_in[25];
    const float* cl_b2 = (const float*)d_in[26];
    const int* src = ei;
    const int* dst = ei + N_EDGES;
    float* out = (float*)d_out;

    char* p = (char*)d_ws;
    auto alloc = [&](size_t bytes) -> char* {
        char* r = p;
        p += (bytes + 255) & ~(size_t)255;
        return r;
    };
    // zeroed region: pk, stats
    char* zero_base = p;
    unsigned long long* pk = (unsigned long long*)alloc(N_NODES*8);
    float* stats = (float*)alloc(4*256*4);
    size_t zero_bytes = (size_t)(p - zero_base);
    int*   rowptr  = (int*)  alloc((N_NODES+1)*4);
    int*   bsum    = (int*)  alloc(64*4);
    int*   rank    = (int*)  alloc((size_t)N_EDGES*4);
    int2*  edge    = (int2*) alloc((size_t)N_EDGES*8);
    float* inv_cnt = (float*)alloc(N_NODES*4);
    float* dis     = (float*)alloc(N_NODES*4);
    ushort* wt1  = (ushort*)alloc(192*128*2);
    ushort* wt2  = (ushort*)alloc(128*128*2);
    ushort* wt3  = (ushort*)alloc(256*128*2);
    ushort* wt4  = (ushort*)alloc(128*128*2);
    ushort* wtF  = (ushort*)alloc(256*128*2);
    ushort* wtC1 = (ushort*)alloc(128*64*2);
    ushort* h0  = (ushort*)alloc((size_t)N_NODES*96*2);
    ushort* AGG = (ushort*)alloc((size_t)N_NODES*128*2);
    ushort* H1  = (ushort*)alloc((size_t)N_NODES*128*2);
    ushort* H2  = (ushort*)alloc((size_t)N_NODES*128*2);
    ushort* H3  = (ushort*)alloc((size_t)N_NODES*128*2);
    ushort* H4 = H3;   // H3 dead after conv4 aggregation
    ushort* HF = H1;   // H1 dead after conv2 aggregation
    ushort* HC = h0;   // h0 dead after conv1 GEMM (N*64 <= N*96)

    hipMemsetAsync(zero_base, 0, zero_bytes, stream);

    prep_w_all<<<512, 256, 0, stream>>>(c1_wl, c1_wr, c2_w, c3_wl, c3_wr, c4_w, fu_w, cl_w1,
                                        wt1, wt2, wt3, wt4, wtF, wtC1);

    encoder_kernel<<<391, 128, 0, stream>>>(x, sp_w1, sp_b1, sp_w2, sp_b2, fe_w, fe_b, h0);

    // CSR
    deg_kernel<<<(N_EDGES+255)/256, 256, 0, stream>>>(dst, ew, pk, rank);
    scan_a<<<(N_NODES+1023)/1024, 1024, 0, stream>>>(pk, rowptr, bsum, inv_cnt, dis);
    scan_c<<<(N_NODES+1+255)/256, 256, 0, stream>>>(rowptr, bsum);
    scatter_kernel<<<(N_EDGES+255)/256, 256, 0, stream>>>(src, dst, ew, dis, rowptr, rank, edge);

    const int GG = (N_NODES + 63) / 64;     // 782
    const int GA = (N_NODES + 15) / 16;     // 3125 (4 waves x 4 nodes per block)

    // conv1 (SAGE, 96 -> 128)
    agg_batch<96,96,48,false><<<GA, 256, 0, stream>>>(h0, rowptr, edge, inv_cnt, AGG);
    gemm_mfma<192,96,128,false,true><<<GG, 256, 0, stream>>>(AGG, 96, h0, 96, wt1, c1_b, H1, 128, stats + 0);
    bnrelu_kernel<<<1024, 256, 0, stream>>>(H1, stats + 0, bn_g + 0, bn_b + 0);

    // conv2 (GCN, 128 -> 128)
    agg_batch<128,128,64,true><<<GA, 256, 0, stream>>>(H1, rowptr, edge, dis, AGG);
    gemm_mfma<128,128,128,false,true><<<GG, 256, 0, stream>>>(AGG, 128, AGG, 128, wt2, c2_b, H2, 128, stats + 256);
    bnrelu_kernel<<<1024, 256, 0, stream>>>(H2, stats + 256, bn_g + 128, bn_b + 128);

    // conv3 (SAGE, 128 -> 128)
    agg_batch<128,128,64,false><<<GA, 256, 0, stream>>>(H2, rowptr, edge, inv_cnt, AGG);
    gemm_mfma<256,128,128,false,true><<<GG, 256, 0, stream>>>(AGG, 128, H2, 128, wt3, c3_b, H3, 128, stats + 512);
    bnrelu_kernel<<<1024, 256, 0, stream>>>(H3, stats + 512, bn_g + 256, bn_b + 256);

    // conv4 (GCN, 128 -> 128)
    agg_batch<128,128,64,true><<<GA, 256, 0, stream>>>(H3, rowptr, edge, dis, AGG);
    gemm_mfma<128,128,128,false,true><<<GG, 256, 0, stream>>>(AGG, 128, AGG, 128, wt4, c4_b, H4, 128, stats + 768);
    bnrelu_kernel<<<1024, 256, 0, stream>>>(H4, stats + 768, bn_g + 384, bn_b + 384);

    // fuse: HF = [H2, H4] @ fu_w + fu_b
    gemm_mfma<256,128,128,false,false><<<GG, 256, 0, stream>>>(H2, 128, H4, 128, wtF, fu_b, HF, 128, nullptr);
    // cl1: HC = relu(HF @ cl_w1 + cl_b1)
    gemm_mfma<128,128,64,true,false><<<GG, 256, 0, stream>>>(HF, 128, HF, 128, wtC1, cl_b1, HC, 64, nullptr);
    // cl2
    cl2_kernel<<<391, 128, 0, stream>>>(HC, cl_w2, cl_b2, out);
}

// Round 8
// 390.070 us; speedup vs baseline: 1.3904x; 1.3904x over previous
//
#include <hip/hip_runtime.h>
#include <hip/hip_bf16.h>
#include <cstdint>

#define N_NODES 50000
#define N_EDGES 800000
#define EPS_BN 1e-5f

typedef short s16x8 __attribute__((ext_vector_type(8)));   // 8 bf16 = 4 VGPRs
typedef float f32x4 __attribute__((ext_vector_type(4)));

__device__ __forceinline__ ushort f2b(float f) {
    uint u = __float_as_uint(f);
    u += 0x7fffu + ((u >> 16) & 1u);
    return (ushort)(u >> 16);
}
__device__ __forceinline__ float b2f(ushort b) {
    return __uint_as_float(((uint)b) << 16);
}

// ---------------- encoder: x(N,19) -> h0(N,96) bf16 = [sp(32), fe(64)] ----------------
__global__ __launch_bounds__(128) void encoder_kernel(
    const float* __restrict__ x,
    const float* __restrict__ sp_w1, const float* __restrict__ sp_b1,
    const float* __restrict__ sp_w2, const float* __restrict__ sp_b2,
    const float* __restrict__ fe_w, const float* __restrict__ fe_b,
    ushort* __restrict__ h0)
{
    __shared__ float w1[96], b1[32], w2[1024], b2[32], wf[1024], bf[64];
    __shared__ float outt[128 * 97];
    int tid = threadIdx.x;
    for (int i = tid; i < 96; i += 128) w1[i] = sp_w1[i];
    for (int i = tid; i < 32; i += 128) { b1[i] = sp_b1[i]; b2[i] = sp_b2[i]; }
    for (int i = tid; i < 1024; i += 128) { w2[i] = sp_w2[i]; wf[i] = fe_w[i]; }
    for (int i = tid; i < 64; i += 128) bf[i] = fe_b[i];
    __syncthreads();
    int n = blockIdx.x * 128 + tid;
    if (n < N_NODES) {
        float c0 = x[n*19+0], c1 = x[n*19+1], c2 = x[n*19+2];
        float ft[16];
        #pragma unroll
        for (int i = 0; i < 16; i++) ft[i] = x[n*19+3+i];
        float t1[32];
        #pragma unroll
        for (int j = 0; j < 32; j++)
            t1[j] = fmaxf(c0*w1[j] + c1*w1[32+j] + c2*w1[64+j] + b1[j], 0.f);
        #pragma unroll 4
        for (int j = 0; j < 32; j++) {
            float a = b2[j];
            #pragma unroll
            for (int k = 0; k < 32; k++) a += t1[k]*w2[k*32+j];
            outt[tid*97+j] = fmaxf(a, 0.f);
        }
        #pragma unroll 4
        for (int j = 0; j < 64; j++) {
            float a = bf[j];
            #pragma unroll
            for (int k = 0; k < 16; k++) a += ft[k]*wf[k*64+j];
            outt[tid*97+32+j] = fmaxf(a, 0.f);
        }
    }
    __syncthreads();
    int base = blockIdx.x * 128;
    int nv = min(128, N_NODES - base);
    for (int i = tid; i < nv*96; i += 128) {
        int r = i / 96, c = i - r*96;
        h0[(size_t)base*96 + i] = f2b(outt[r*97 + c]);
    }
}

// ---------------- CSR build ----------------
// One packed 64-bit atomic per edge: count in bits [40,64), degw in 23.0 fixed point
// below (max sum ~2^30 << 2^40, no carry into count). Returned old>>40 = edge rank.
__global__ void deg_kernel(const int* __restrict__ dst, const float* __restrict__ ew,
                           unsigned long long* __restrict__ pk, int* __restrict__ rank)
{
    int e = blockIdx.x*256 + threadIdx.x;
    if (e < N_EDGES) {
        int d = dst[e];
        unsigned long long inc = (1ull << 40)
            + (unsigned long long)(uint)(ew[e]*8388608.f + 0.5f);
        unsigned long long old = atomicAdd(&pk[d], inc);
        rank[e] = (int)(old >> 40);
    }
}

// scan phase A (+ fused prep): per-1024 chunk exclusive scan + chunk totals
__global__ __launch_bounds__(1024) void scan_a(const unsigned long long* __restrict__ pk,
                                               int* __restrict__ rowptr,
                                               int* __restrict__ bsum,
                                               float* __restrict__ inv_cnt,
                                               float* __restrict__ dis)
{
    __shared__ int wsum[16];
    int tid = threadIdx.x;
    int i = blockIdx.x*1024 + tid;
    int v = 0;
    if (i < N_NODES) {
        unsigned long long u = pk[i];
        v = (int)(u >> 40);
        float dw = (float)(u & ((1ull<<40)-1)) * (1.f/8388608.f);
        inv_cnt[i] = 1.f / (float)max(v, 1);
        dis[i] = rsqrtf(dw + 1.f);   // +1 self-loop weight; always > 0
    }
    int lane = tid & 63, wid = tid >> 6;
    int incl = v;
    #pragma unroll
    for (int off = 1; off < 64; off <<= 1) {
        int t = __shfl_up(incl, off);
        if (lane >= off) incl += t;
    }
    if (lane == 63) wsum[wid] = incl;
    __syncthreads();
    if (wid == 0 && lane < 16) {
        int s = wsum[lane];
        #pragma unroll
        for (int off = 1; off < 16; off <<= 1) {
            int t = __shfl_up(s, off);
            if (lane >= off) s += t;
        }
        wsum[lane] = s;
    }
    __syncthreads();
    int base = (wid > 0) ? wsum[wid-1] : 0;
    if (i < N_NODES) rowptr[i] = base + incl - v;
    if (tid == 1023) bsum[blockIdx.x] = base + incl;
}

// scan phase C (fused B): every block re-scans the 49 chunk totals in wave 0
__global__ __launch_bounds__(256) void scan_c(int* __restrict__ rowptr,
                                              const int* __restrict__ bsum)
{
    __shared__ int boff[64];
    int tid = threadIdx.x;
    if (tid < 64) {
        const int NC = (N_NODES + 1023) >> 10;   // 49
        int v = (tid < NC) ? bsum[tid] : 0;
        int incl = v;
        #pragma unroll
        for (int off = 1; off < 64; off <<= 1) {
            int t = __shfl_up(incl, off);
            if (tid >= off) incl += t;
        }
        boff[tid] = incl - v;   // exclusive; boff[NC] = grand total
    }
    __syncthreads();
    int i = blockIdx.x*256 + tid;
    if (i < N_NODES) rowptr[i] += boff[i >> 10];
    else if (i == N_NODES) rowptr[i] = boff[(N_NODES + 1023) >> 10];
}

// scatter (no atomics): pos = rowptr[dst] + rank; edge = {src, ew*dis[src]}
__global__ void scatter_kernel(const int* __restrict__ src, const int* __restrict__ dst,
                               const float* __restrict__ ew, const float* __restrict__ dis,
                               const int* __restrict__ rowptr, const int* __restrict__ rank,
                               int2* __restrict__ edge)
{
    int e = blockIdx.x*256 + threadIdx.x;
    if (e < N_EDGES) {
        int d = dst[e];
        int s = src[e];
        int pos = rowptr[d] + rank[e];
        edge[pos] = make_int2(s, __float_as_int(ew[e] * dis[s]));
    }
}

// ---------------- aggregation (bf16 h, one wave per node, lane = 2 feats) ----------------
// 16-wide masked main loop, NO scalar tail: out-of-range slots clamp to edge[beg]
// with weight/mask 0. beg/end readfirstlane'd (wave-uniform loop bounds); edge values
// stay in VECTOR registers (R7 lesson: scalarizing them serializes the gather stream).
__global__ __launch_bounds__(256) void sage_agg(
    const ushort* __restrict__ h, int ldh, int D2,
    const int* __restrict__ rowptr, const int2* __restrict__ edge,
    const float* __restrict__ inv_cnt,
    ushort* __restrict__ out, int ldo)
{
    int w = threadIdx.x >> 6, l = threadIdx.x & 63;
    int n = blockIdx.x*4 + w;
    if (n >= N_NODES) return;
    int beg = __builtin_amdgcn_readfirstlane(rowptr[n]);
    int end = __builtin_amdgcn_readfirstlane(rowptr[n+1]);
    bool act = l < D2;
    int off = 2*l;
    float ax = 0.f, ay = 0.f;
    for (int j = beg; j < end; j += 16) {
        int ss[16]; float m[16];
        #pragma unroll
        for (int q = 0; q < 16; q++) {
            bool ok = (j + q < end);
            ss[q] = edge[ok ? j + q : beg].x;
            m[q] = ok ? 1.f : 0.f;
        }
        if (act) {
            uint u[16];
            #pragma unroll
            for (int q = 0; q < 16; q++) u[q] = *(const uint*)(h + (size_t)ss[q]*ldh + off);
            #pragma unroll
            for (int q = 0; q < 16; q++) {
                ax = fmaf(m[q], __uint_as_float(u[q]<<16), ax);
                ay = fmaf(m[q], __uint_as_float(u[q] & 0xffff0000u), ay);
            }
        }
    }
    if (act) {
        float ic = inv_cnt[n];
        uint o = (uint)f2b(ax*ic) | ((uint)f2b(ay*ic) << 16);
        *(uint*)(out + (size_t)n*ldo + off) = o;
    }
}

// GCN agg with OPTIONAL fused BN+ReLU on the gathered input (BN of the producer layer).
// Each lane computes scale/shift for its 2 features from stats once (~10 ops), then
// applies relu(x*sc+sh) per gathered element. Removes standalone bnrelu passes for
// H1/H3 (single-consumer post-BN tensors).
template<bool BN>
__global__ __launch_bounds__(256) void gcn_agg(
    const ushort* __restrict__ h,
    const int* __restrict__ rowptr, const int2* __restrict__ edge,
    const float* __restrict__ dis,
    const float* __restrict__ stats, const float* __restrict__ g,
    const float* __restrict__ b,
    ushort* __restrict__ out)
{
    int w = threadIdx.x >> 6, l = threadIdx.x & 63;
    int n = blockIdx.x*4 + w;
    if (n >= N_NODES) return;
    int beg = __builtin_amdgcn_readfirstlane(rowptr[n]);
    int end = __builtin_amdgcn_readfirstlane(rowptr[n+1]);
    int off = 2*l;

    float sc0 = 1.f, sh0 = 0.f, sc1 = 1.f, sh1 = 0.f;
    if (BN) {
        float mu0  = stats[off]     * (1.f/N_NODES);
        float var0 = stats[128+off] * (1.f/N_NODES) - mu0*mu0;
        sc0 = g[off] * rsqrtf(var0 + EPS_BN);
        sh0 = b[off] - mu0*sc0;
        float mu1  = stats[off+1]     * (1.f/N_NODES);
        float var1 = stats[128+off+1] * (1.f/N_NODES) - mu1*mu1;
        sc1 = g[off+1] * rsqrtf(var1 + EPS_BN);
        sh1 = b[off+1] - mu1*sc1;
    }

    float ax = 0.f, ay = 0.f;
    for (int j = beg; j < end; j += 16) {
        int ss[16]; float wq[16];
        #pragma unroll
        for (int q = 0; q < 16; q++) {
            bool ok = (j + q < end);
            int2 e = edge[ok ? j + q : beg];
            ss[q] = e.x;
            wq[q] = ok ? __int_as_float(e.y) : 0.f;
        }
        uint u[16];
        #pragma unroll
        for (int q = 0; q < 16; q++) u[q] = *(const uint*)(h + (size_t)ss[q]*128 + off);
        #pragma unroll
        for (int q = 0; q < 16; q++) {
            float x0 = __uint_as_float(u[q]<<16);
            float x1 = __uint_as_float(u[q] & 0xffff0000u);
            if (BN) {
                x0 = fmaxf(fmaf(x0, sc0, sh0), 0.f);
                x1 = fmaxf(fmaf(x1, sc1, sh1), 0.f);
            }
            ax = fmaf(wq[q], x0, ax);
            ay = fmaf(wq[q], x1, ay);
        }
    }
    float dn = dis[n];
    uint us = *(const uint*)(h + (size_t)n*128 + off);
    float sx = __uint_as_float(us<<16), sy = __uint_as_float(us & 0xffff0000u);
    if (BN) {
        sx = fmaxf(fmaf(sx, sc0, sh0), 0.f);
        sy = fmaxf(fmaf(sy, sc1, sh1), 0.f);
    }
    float rx = dn*ax + dn*dn*sx;
    float ry = dn*ay + dn*dn*sy;
    uint o = (uint)f2b(rx) | ((uint)f2b(ry) << 16);
    *(uint*)(out + (size_t)n*128 + off) = o;
}

// ---------------- weight prep: all 6 weights in one kernel ----------------
__device__ __forceinline__ void wprep(int idx, int K1, int KT, int NOUT,
                                      const float* __restrict__ w1,
                                      const float* __restrict__ w2,
                                      ushort* __restrict__ dst)
{
    int k = idx / NOUT, c = idx - k*NOUT;
    float v = (k < K1) ? w1[idx] : w2[idx - K1*NOUT];
    dst[c*KT + k] = f2b(v);
}

__global__ void prep_w_all(
    const float* __restrict__ c1_wl, const float* __restrict__ c1_wr,
    const float* __restrict__ c2_w,  const float* __restrict__ c3_wl,
    const float* __restrict__ c3_wr, const float* __restrict__ c4_w,
    const float* __restrict__ fu_w,  const float* __restrict__ cl_w1,
    ushort* __restrict__ wt1, ushort* __restrict__ wt2, ushort* __restrict__ wt3,
    ushort* __restrict__ wt4, ushort* __restrict__ wtF, ushort* __restrict__ wtC1)
{
    int idx = blockIdx.x*256 + threadIdx.x;
    if      (idx <  24576) wprep(idx,          96, 192, 128, c1_wl, c1_wr, wt1);
    else if (idx <  40960) wprep(idx - 24576, 128, 128, 128, c2_w,  c2_w,  wt2);
    else if (idx <  73728) wprep(idx - 40960, 128, 256, 128, c3_wl, c3_wr, wt3);
    else if (idx <  90112) wprep(idx - 73728, 128, 128, 128, c4_w,  c4_w,  wt4);
    else if (idx < 122880) wprep(idx - 90112, 128, 256, 128, fu_w,  fu_w + 16384, wtF);
    else if (idx < 131072) wprep(idx - 122880,128, 128,  64, cl_w1, cl_w1, wtC1);
}

// ---------------- MFMA GEMM: C = [A1|A2] @ W + bias (bf16 in, bf16 out, fp32 acc) -----
// 64 rows/block (4 waves x 16 rows). W staged into LDS in K-chunks of 128 (padded rows,
// 2-way-free bank pattern); A fragments (the HBM stream) fully prefetched up front so
// their latency hides under W staging. Epilogue reuses the W LDS (dead) for coalesced
// store staging + BN stats reduction.
template<int KT, int K1, int NOUT, bool RELU, bool STATS>
__global__ __launch_bounds__(256, 4) void gemm_mfma(
    const ushort* __restrict__ A1, int lda1,
    const ushort* __restrict__ A2, int lda2,
    const ushort* __restrict__ Wt,
    const float* __restrict__ bias,
    ushort* __restrict__ C, int ldc,
    float* __restrict__ stats)
{
    constexpr int NCF = NOUT/16;            // 16-col fragments
    constexpr int LW  = 136;                // padded LDS W row (ushorts): 128 + 8
    constexpr int LC  = NOUT + 8;           // padded cst row
    constexpr int NPH = (KT + 127)/128;     // K chunks
    __shared__ __align__(16) char smem[NOUT*LW*2];
    ushort (*wlds)[LW] = (ushort(*)[LW])smem;                   // phase-live
    ushort (*cst)[16][LC] = (ushort(*)[16][LC])smem;            // epilogue (W dead)
    float* red = (float*)(smem + 4*16*LC*2);                    // after cst

    int tid = threadIdx.x;
    int w = tid >> 6, l = tid & 63;
    int l15 = l & 15, l4 = l >> 4;
    int rb = blockIdx.x*64 + w*16;

    int rowA = min(rb + l15, N_NODES-1);
    const ushort* pa1 = A1 + (size_t)rowA*lda1 + 8*l4;
    const ushort* pa2 = A2 + (size_t)rowA*lda2 + 8*l4;

    // prefetch ALL A fragments (independent dwordx4 HBM loads, hide under W staging)
    s16x8 a[KT/32];
    #pragma unroll
    for (int ks = 0; ks < KT/32; ks++) {
        const int k0 = ks*32;
        a[ks] = *(const s16x8*)((k0 < K1) ? (pa1 + k0) : (pa2 + (k0 - K1)));
    }

    f32x4 acc[NCF];
    #pragma unroll
    for (int cf = 0; cf < NCF; cf++) acc[cf] = (f32x4){0.f, 0.f, 0.f, 0.f};

    #pragma unroll
    for (int ph = 0; ph < NPH; ph++) {
        const int kb = ph*128;
        const int ck = (KT - kb < 128) ? (KT - kb) : 128;
        // stage W[:, kb:kb+ck] -> wlds (coalesced global read, padded LDS write)
        for (int c = tid; c < NOUT*(ck/8); c += 256) {
            int row = c / (ck/8), kc = c - row*(ck/8);
            s16x8 v = *(const s16x8*)(Wt + (size_t)row*KT + kb + kc*8);
            *(s16x8*)&wlds[row][kc*8] = v;
        }
        __syncthreads();
        #pragma unroll
        for (int kl = 0; kl < 128; kl += 32) {
            if (kl < ck) {
                s16x8 b[NCF];
                #pragma unroll
                for (int cf = 0; cf < NCF; cf++)
                    b[cf] = *(const s16x8*)&wlds[cf*16 + l15][kl + 8*l4];
                #pragma unroll
                for (int cf = 0; cf < NCF; cf++)
                    acc[cf] = __builtin_amdgcn_mfma_f32_16x16x32_bf16(a[(kb+kl)/32], b[cf], acc[cf], 0, 0, 0);
            }
        }
        __syncthreads();   // wlds dead after last phase -> safe to reuse as cst
    }

    // epilogue: bias(+relu), stats partials, stage to LDS (per-wave region, no barrier)
    float r1[NCF], r2[NCF];
    #pragma unroll
    for (int cf = 0; cf < NCF; cf++) {
        int colc = cf*16 + l15;
        float bv = bias[colc];
        float s1 = 0.f, s2 = 0.f;
        #pragma unroll
        for (int reg = 0; reg < 4; reg++) {
            int lr = l4*4 + reg;
            float v = acc[cf][reg] + bv;
            if (RELU) v = fmaxf(v, 0.f);
            if (STATS && (rb + lr < N_NODES)) { s1 += v; s2 += v*v; }
            cst[w][lr][colc] = f2b(v);
        }
        if (STATS) {
            s1 += __shfl_xor(s1, 16); s1 += __shfl_xor(s1, 32);
            s2 += __shfl_xor(s2, 16); s2 += __shfl_xor(s2, 32);
            r1[cf] = s1; r2[cf] = s2;
        }
    }

    // coalesced store-back (wave-private cst; in-wave lgkmcnt ordering only)
    constexpr int CHK = NOUT/8;              // 16B chunks per row
    constexpr int RPI = 64/CHK;              // rows per instruction
    #pragma unroll
    for (int it = 0; it < 16/RPI; it++) {
        int lr = it*RPI + l/CHK;
        int ck2 = l % CHK;
        int r = rb + lr;
        if (r < N_NODES) {
            s16x8 v = *(const s16x8*)&cst[w][lr][ck2*8];
            *(s16x8*)&C[(size_t)r*ldc + ck2*8] = v;
        }
    }

    if (STATS) {
        for (int i = tid; i < 2*NOUT; i += 256) red[i] = 0.f;
        __syncthreads();
        if (l4 == 0) {
            #pragma unroll
            for (int cf = 0; cf < NCF; cf++) {
                atomicAdd(&red[cf*16 + l15], r1[cf]);
                atomicAdd(&red[NOUT + cf*16 + l15], r2[cf]);
            }
        }
        __syncthreads();
        for (int i = tid; i < 2*NOUT; i += 256)
            atomicAdd(&stats[i], red[i]);
    }
}

// ---------------- BN + ReLU in place on bf16 (N x 128) ----------------
__global__ __launch_bounds__(256) void bnrelu_kernel(
    ushort* __restrict__ h, const float* __restrict__ stats,
    const float* __restrict__ g, const float* __restrict__ b)
{
    __shared__ float sc[128], sh[128];
    int tid = threadIdx.x;
    if (tid < 128) {
        float mu  = stats[tid] * (1.f/N_NODES);
        float var = stats[128+tid] * (1.f/N_NODES) - mu*mu;
        float s = g[tid] * rsqrtf(var + EPS_BN);
        sc[tid] = s;
        sh[tid] = b[tid] - mu*s;
    }
    __syncthreads();
    const int total = N_NODES * 16;   // uint4 chunks of 8 bf16
    for (int i = blockIdx.x*256 + tid; i < total; i += gridDim.x*256) {
        uint4 u = ((const uint4*)h)[i];
        int c = (i & 15) * 8;
        float v0 = __uint_as_float(u.x<<16),  v1 = __uint_as_float(u.x & 0xffff0000u);
        float v2 = __uint_as_float(u.y<<16),  v3 = __uint_as_float(u.y & 0xffff0000u);
        float v4 = __uint_as_float(u.z<<16),  v5 = __uint_as_float(u.z & 0xffff0000u);
        float v6 = __uint_as_float(u.w<<16),  v7 = __uint_as_float(u.w & 0xffff0000u);
        v0 = fmaxf(v0*sc[c+0] + sh[c+0], 0.f);
        v1 = fmaxf(v1*sc[c+1] + sh[c+1], 0.f);
        v2 = fmaxf(v2*sc[c+2] + sh[c+2], 0.f);
        v3 = fmaxf(v3*sc[c+3] + sh[c+3], 0.f);
        v4 = fmaxf(v4*sc[c+4] + sh[c+4], 0.f);
        v5 = fmaxf(v5*sc[c+5] + sh[c+5], 0.f);
        v6 = fmaxf(v6*sc[c+6] + sh[c+6], 0.f);
        v7 = fmaxf(v7*sc[c+7] + sh[c+7], 0.f);
        u.x = (uint)f2b(v0) | ((uint)f2b(v1)<<16);
        u.y = (uint)f2b(v2) | ((uint)f2b(v3)<<16);
        u.z = (uint)f2b(v4) | ((uint)f2b(v5)<<16);
        u.w = (uint)f2b(v6) | ((uint)f2b(v7)<<16);
        ((uint4*)h)[i] = u;
    }
}

// ---------------- classifier head 2: out = hc(N,64)bf16 @ w2(64,10) + b2 -> fp32 ----------
__global__ __launch_bounds__(128) void cl2_kernel(
    const ushort* __restrict__ hc, const float* __restrict__ w2,
    const float* __restrict__ b2, float* __restrict__ out)
{
    __shared__ float tile[128][65];
    __shared__ float wl[640];
    __shared__ float bl[16];
    __shared__ float ol[1280];
    int tid = threadIdx.x;
    int base = blockIdx.x * 128;
    int nv = min(128, N_NODES - base);
    for (int i = tid; i < 640; i += 128) wl[i] = w2[i];
    if (tid < 10) bl[tid] = b2[tid];
    for (int i = tid; i < nv*64; i += 128) {
        int r = i >> 6, c = i & 63;
        tile[r][c] = b2f(hc[(size_t)base*64 + i]);
    }
    __syncthreads();
    if (tid < nv) {
        float o[10];
        #pragma unroll
        for (int j = 0; j < 10; j++) o[j] = bl[j];
        #pragma unroll 4
        for (int k = 0; k < 64; k++) {
            float hv = tile[tid][k];
            #pragma unroll
            for (int j = 0; j < 10; j++) o[j] += hv * wl[k*10+j];
        }
        #pragma unroll
        for (int j = 0; j < 10; j++) ol[tid*10+j] = o[j];
    }
    __syncthreads();
    for (int i = tid; i < nv*10; i += 128) out[(size_t)base*10 + i] = ol[i];
}

// ---------------- launch ----------------
extern "C" void kernel_launch(void* const* d_in, const int* in_sizes, int n_in,
                              void* d_out, int out_size, void* d_ws, size_t ws_size,
                              hipStream_t stream)
{
    const float* x     = (const float*)d_in[0];
    const int*   ei    = (const int*)  d_in[1];
    const float* ew    = (const float*)d_in[2];
    const float* sp_w1 = (const float*)d_in[3];
    const float* sp_b1 = (const float*)d_in[4];
    const float* sp_w2 = (const float*)d_in[5];
    const float* sp_b2 = (const float*)d_in[6];
    const float* fe_w  = (const float*)d_in[7];
    const float* fe_b  = (const float*)d_in[8];
    const float* c1_wl = (const float*)d_in[9];
    const float* c1_wr = (const float*)d_in[10];
    const float* c1_b  = (const float*)d_in[11];
    const float* c2_w  = (const float*)d_in[12];
    const float* c2_b  = (const float*)d_in[13];
    const float* c3_wl = (const float*)d_in[14];
    const float* c3_wr = (const float*)d_in[15];
    const float* c3_b  = (const float*)d_in[16];
    const float* c4_w  = (const float*)d_in[17];
    const float* c4_b  = (const float*)d_in[18];
    const float* bn_g  = (const float*)d_in[19];
    const float* bn_b  = (const float*)d_in[20];
    const float* fu_w  = (const float*)d_in[21];
    const float* fu_b  = (const float*)d_in[22];
    const float* cl_w1 = (const float*)d_in[23];
    const float* cl_b1 = (const float*)d_in[24];
    const float* cl_w2 = (const float*)d_in[25];
    const float* cl_b2 = (const float*)d_in[26];
    const int* src = ei;
    const int* dst = ei + N_EDGES;
    float* out = (float*)d_out;

    char* p = (char*)d_ws;
    auto alloc = [&](size_t bytes) -> char* {
        char* r = p;
        p += (bytes + 255) & ~(size_t)255;
        return r;
    };
    // zeroed region: pk, stats
    char* zero_base = p;
    unsigned long long* pk = (unsigned long long*)alloc(N_NODES*8);
    float* stats = (float*)alloc(4*256*4);
    size_t zero_bytes = (size_t)(p - zero_base);
    int*   rowptr  = (int*)  alloc((N_NODES+1)*4);
    int*   bsum    = (int*)  alloc(64*4);
    int*   rank    = (int*)  alloc((size_t)N_EDGES*4);
    int2*  edge    = (int2*) alloc((size_t)N_EDGES*8);
    float* inv_cnt = (float*)alloc(N_NODES*4);
    float* dis     = (float*)alloc(N_NODES*4);
    ushort* wt1  = (ushort*)alloc(192*128*2);
    ushort* wt2  = (ushort*)alloc(128*128*2);
    ushort* wt3  = (ushort*)alloc(256*128*2);
    ushort* wt4  = (ushort*)alloc(128*128*2);
    ushort* wtF  = (ushort*)alloc(256*128*2);
    ushort* wtC1 = (ushort*)alloc(128*64*2);
    ushort* h0  = (ushort*)alloc((size_t)N_NODES*96*2);
    ushort* AGG = (ushort*)alloc((size_t)N_NODES*128*2);
    ushort* H1  = (ushort*)alloc((size_t)N_NODES*128*2);
    ushort* H2  = (ushort*)alloc((size_t)N_NODES*128*2);
    ushort* H3  = (ushort*)alloc((size_t)N_NODES*128*2);
    ushort* H4 = H3;   // H3 dead after conv4 aggregation
    ushort* HF = H1;   // H1 dead after conv2 aggregation
    ushort* HC = h0;   // h0 dead after conv1 GEMM (N*64 <= N*96)

    hipMemsetAsync(zero_base, 0, zero_bytes, stream);

    prep_w_all<<<512, 256, 0, stream>>>(c1_wl, c1_wr, c2_w, c3_wl, c3_wr, c4_w, fu_w, cl_w1,
                                        wt1, wt2, wt3, wt4, wtF, wtC1);

    encoder_kernel<<<391, 128, 0, stream>>>(x, sp_w1, sp_b1, sp_w2, sp_b2, fe_w, fe_b, h0);

    // CSR
    deg_kernel<<<(N_EDGES+255)/256, 256, 0, stream>>>(dst, ew, pk, rank);
    scan_a<<<(N_NODES+1023)/1024, 1024, 0, stream>>>(pk, rowptr, bsum, inv_cnt, dis);
    scan_c<<<(N_NODES+1+255)/256, 256, 0, stream>>>(rowptr, bsum);
    scatter_kernel<<<(N_EDGES+255)/256, 256, 0, stream>>>(src, dst, ew, dis, rowptr, rank, edge);

    const int GG = (N_NODES + 63) / 64;     // 782
    const int GA = (N_NODES + 3) / 4;       // 12500

    // conv1 (SAGE, 96 -> 128); H1 stays PRE-BN (BN folded into conv2's gcn_agg)
    sage_agg<<<GA, 256, 0, stream>>>(h0, 96, 48, rowptr, edge, inv_cnt, AGG, 96);
    gemm_mfma<192,96,128,false,true><<<GG, 256, 0, stream>>>(AGG, 96, h0, 96, wt1, c1_b, H1, 128, stats + 0);

    // conv2 (GCN, 128 -> 128), BN1+ReLU fused into the gather
    gcn_agg<true><<<GA, 256, 0, stream>>>(H1, rowptr, edge, dis, stats + 0, bn_g + 0, bn_b + 0, AGG);
    gemm_mfma<128,128,128,false,true><<<GG, 256, 0, stream>>>(AGG, 128, AGG, 128, wt2, c2_b, H2, 128, stats + 256);
    bnrelu_kernel<<<1024, 256, 0, stream>>>(H2, stats + 256, bn_g + 128, bn_b + 128);

    // conv3 (SAGE, 128 -> 128); H3 stays PRE-BN (BN folded into conv4's gcn_agg)
    sage_agg<<<GA, 256, 0, stream>>>(H2, 128, 64, rowptr, edge, inv_cnt, AGG, 128);
    gemm_mfma<256,128,128,false,true><<<GG, 256, 0, stream>>>(AGG, 128, H2, 128, wt3, c3_b, H3, 128, stats + 512);

    // conv4 (GCN, 128 -> 128), BN3+ReLU fused into the gather
    gcn_agg<true><<<GA, 256, 0, stream>>>(H3, rowptr, edge, dis, stats + 512, bn_g + 256, bn_b + 256, AGG);
    gemm_mfma<128,128,128,false,true><<<GG, 256, 0, stream>>>(AGG, 128, AGG, 128, wt4, c4_b, H4, 128, stats + 768);
    bnrelu_kernel<<<1024, 256, 0, stream>>>(H4, stats + 768, bn_g + 384, bn_b + 384);

    // fuse: HF = [H2, H4] @ fu_w + fu_b
    gemm_mfma<256,128,128,false,false><<<GG, 256, 0, stream>>>(H2, 128, H4, 128, wtF, fu_b, HF, 128, nullptr);
    // cl1: HC = relu(HF @ cl_w1 + cl_b1)
    gemm_mfma<128,128,64,true,false><<<GG, 256, 0, stream>>>(HF, 128, HF, 128, wtC1, cl_b1, HC, 64, nullptr);
    // cl2
    cl2_kernel<<<391, 128, 0, stream>>>(HC, cl_w2, cl_b2, out);
}